// Round 6
// baseline (1413.131 us; speedup 1.0000x reference)
//
#include <hip/hip_runtime.h>

#define BB 8192
#define TT 10
#define FF 561
#define FP 576   // 561 padded to 18*32
#define HH 256
#define OO 12

typedef __attribute__((ext_vector_type(8))) __bf16 bf16x8;
typedef __attribute__((ext_vector_type(4))) float f32x4;

__device__ __forceinline__ unsigned short f2bf(float f) {
  unsigned int u = __float_as_uint(f);
  u += 0x7fffu + ((u >> 16) & 1u);   // round-to-nearest-even
  return (unsigned short)(u >> 16);
}
__device__ __forceinline__ float sigm(float x) { return 1.f / (1.f + __expf(-x)); }
__device__ __forceinline__ float tanh_fast(float x) { return 1.f - 2.f / (__expf(2.f * x) + 1.f); }

__device__ __forceinline__ void gl_lds16(const unsigned short* g, unsigned short* l) {
  __builtin_amdgcn_global_load_lds(
      (const __attribute__((address_space(1))) unsigned int*)g,
      (__attribute__((address_space(3))) unsigned int*)l, 16, 0, 0);
}

// 128x128 tile worth of MFMA from one LDS A/B buffer (BK=32) — used by gemm_xp
__device__ __forceinline__ void mfma_tile(const unsigned short* as, const unsigned short* bs,
                                          int w, int quad, int l15, f32x4 (&acc)[2][8]) {
  bf16x8 af[2], bfr[8];
#pragma unroll
  for (int mt = 0; mt < 2; ++mt)
    af[mt] = *(const bf16x8*)&as[(w * 32 + mt * 16 + l15) * 32 + quad * 8];
#pragma unroll
  for (int nt = 0; nt < 8; ++nt)
    bfr[nt] = *(const bf16x8*)&bs[(nt * 16 + l15) * 32 + quad * 8];
#pragma unroll
  for (int mt = 0; mt < 2; ++mt)
#pragma unroll
    for (int nt = 0; nt < 8; ++nt)
      acc[mt][nt] = __builtin_amdgcn_mfma_f32_16x16x32_bf16(af[mt], bfr[nt], acc[mt][nt], 0, 0, 0);
}

// Convert inputs [81920,561] f32 -> bf16 zero-padded [81920,576]
__global__ void conv_inputs(const float* __restrict__ in, unsigned short* __restrict__ Ain) {
  int idx = blockIdx.x * 256 + threadIdx.x;  // over 81920*144, 4 elems each
  if (idx >= 81920 * 144) return;
  int c4 = (idx % 144) * 4;
  size_t row = idx / 144;
  const float* src = in + row * 561 + c4;
  ushort4 v;
  v.x = f2bf(c4 + 0 < 561 ? src[0] : 0.f);
  v.y = f2bf(c4 + 1 < 561 ? src[1] : 0.f);
  v.z = f2bf(c4 + 2 < 561 ? src[2] : 0.f);
  v.w = f2bf(c4 + 3 < 561 ? src[3] : 0.f);
  *(ushort4*)(Ain + row * 576 + c4) = v;
}

// Build bf16 weights + combined biases.
//  Wib [256][576]: W_inp zero-padded.
//  W0p/W1p [1024][512]: permuted fused [Wih|Whh]. NEW permutation (gate-quad per
//  16-h-group): n' -> hq=n'>>6, g=(n'>>4)&3, hl=n'&15; src row = g*256 + hq*16 + hl.
//  So cols [cw*64, cw*64+64) = gates {i,f,g,o} x h-cols [cw*16, cw*16+16).
//  Wob [16][256], bc0/bc1 [1024] = bih+bhh (f32, original gate-major).
__global__ void conv_weights(const float* __restrict__ Winp,
                             const float* __restrict__ Wih0, const float* __restrict__ Whh0,
                             const float* __restrict__ Wih1, const float* __restrict__ Whh1,
                             const float* __restrict__ Wout,
                             const float* __restrict__ bih0, const float* __restrict__ bhh0,
                             const float* __restrict__ bih1, const float* __restrict__ bhh1,
                             unsigned short* __restrict__ Wib,
                             unsigned short* __restrict__ W0p,
                             unsigned short* __restrict__ W1p,
                             unsigned short* __restrict__ Wob,
                             float* __restrict__ bc0, float* __restrict__ bc1) {
  int idx = blockIdx.x * 256 + threadIdx.x;
  if (idx < 256 * 576) {
    int kk = idx % 576, n = idx / 576;
    Wib[idx] = f2bf(kk < 561 ? Winp[n * 561 + kk] : 0.f);
    return;
  }
  idx -= 256 * 576;
  if (idx < 1024 * 512) {
    int kk = idx % 512, np = idx / 512;
    int hq = np >> 6, g = (np >> 4) & 3, hl = np & 15;
    int sr = g * 256 + hq * 16 + hl;
    float v = kk < 256 ? Wih0[sr * 256 + kk] : Whh0[sr * 256 + kk - 256];
    W0p[idx] = f2bf(v);
    return;
  }
  idx -= 1024 * 512;
  if (idx < 1024 * 512) {
    int kk = idx % 512, np = idx / 512;
    int hq = np >> 6, g = (np >> 4) & 3, hl = np & 15;
    int sr = g * 256 + hq * 16 + hl;
    float v = kk < 256 ? Wih1[sr * 256 + kk] : Whh1[sr * 256 + kk - 256];
    W1p[idx] = f2bf(v);
    return;
  }
  idx -= 1024 * 512;
  if (idx < 16 * 256) {
    int kk = idx % 256, o = idx / 256;
    Wob[idx] = f2bf(o < OO ? Wout[o * 256 + kk] : 0.f);
    return;
  }
  idx -= 16 * 256;
  if (idx < 1024) { bc0[idx] = bih0[idx] + bhh0[idx]; return; }
  idx -= 1024;
  if (idx < 1024) { bc1[idx] = bih1[idx] + bhh1[idx]; }
}

// xp GEMM: xp[81920,256] = Ain @ Wib^T + b_inp. M=81920 N=256 K=576. (unchanged)
__global__ __launch_bounds__(256, 2) void gemm_xp(
    const unsigned short* __restrict__ A, const unsigned short* __restrict__ W,
    const float* __restrict__ bias, unsigned short* __restrict__ xp) {
  __shared__ __align__(16) unsigned short As[2][128 * 32];
  __shared__ __align__(16) unsigned short Bs[2][128 * 32];
  const int tid = threadIdx.x;
  const int w = tid >> 6, lane = tid & 63, quad = lane >> 4, l15 = lane & 15;
  const int flat = blockIdx.x;
  const int xcd = flat & 7, kb = flat >> 3;     // kb in [0,160)
  const int nb = kb & 1, mb = xcd * 80 + (kb >> 1);
  const int r0 = tid >> 2, cc = (tid & 3) * 8;

  auto stage = [&](int buf, int k0) {
    gl_lds16(A + (size_t)(mb * 128 + r0) * FP + k0 + cc, &As[buf][tid * 8]);
    gl_lds16(A + (size_t)(mb * 128 + 64 + r0) * FP + k0 + cc, &As[buf][2048 + tid * 8]);
    gl_lds16(W + (size_t)(nb * 128 + r0) * FP + k0 + cc, &Bs[buf][tid * 8]);
    gl_lds16(W + (size_t)(nb * 128 + 64 + r0) * FP + k0 + cc, &Bs[buf][2048 + tid * 8]);
  };

  f32x4 acc[2][8];
#pragma unroll
  for (int i = 0; i < 2; ++i)
#pragma unroll
    for (int j = 0; j < 8; ++j) acc[i][j] = (f32x4){0.f, 0.f, 0.f, 0.f};

  stage(0, 0);
  __syncthreads();
  int cur = 0;
#pragma unroll
  for (int ks = 0; ks < 17; ++ks) {
    stage(cur ^ 1, (ks + 1) * 32);
    mfma_tile(&As[cur][0], &Bs[cur][0], w, quad, l15, acc);
    __syncthreads();
    cur ^= 1;
  }
  mfma_tile(&As[cur][0], &Bs[cur][0], w, quad, l15, acc);

#pragma unroll
  for (int mt = 0; mt < 2; ++mt) {
    int rowb = mb * 128 + w * 32 + mt * 16 + quad * 4;
#pragma unroll
    for (int nt = 0; nt < 8; ++nt) {
      int col = nb * 128 + nt * 16 + l15;
      float bv = bias[col];
#pragma unroll
      for (int r = 0; r < 4; ++r)
        xp[(size_t)(rowb + r) * HH + col] = f2bf(acc[mt][nt][r] + bv);
    }
  }
}

struct RArgs {
  const unsigned short* xp;   // [81920][256], row m = b*TT + t
  unsigned short* hs;         // [(T+1)][B][H], slots 1..T written here
  const unsigned short* W0p;  // [1024][512] gate-quad permuted
  const unsigned short* W1p;
  const float* bc0;           // [1024] bih0+bhh0, gate-major
  const float* bc1;
  float* hn;                  // [2][B][H] f32 out
  float* cn;
};

// Exchange-free persistent LSTM, occupancy-rebuilt (round-5 was 1 wave/SIMD,
// latency-bound on direct W L2 loads). 256 blocks x 1024 threads (16 waves);
// block owns 32 batch rows end-to-end (no inter-block comm, no fences).
// Wave cw: all 32 rows x gate-cols [cw*64, cw*64+64) = 4 gates x h-cols
// [cw*16,+16) (new W permutation) -> acc[2][4] (32 regs), c-state f32x4[2]/layer.
// B software-pipelined (ks+1 fragments loaded before ks MFMAs). A: xp direct
// from L1/L2 (16-wave reuse), h from padded LDS. ~115 unified regs/wave ->
// 4 waves/SIMD. 3 barriers per timestep.
__global__ __launch_bounds__(1024, 4) void lstm_rows(RArgs p) {
  __shared__ __align__(16) unsigned short h0l[32 * 264];
  __shared__ __align__(16) unsigned short h1l[32 * 264];
  const int tid = threadIdx.x;
  const int cw = tid >> 6, lane = tid & 63, q4 = lane >> 4, l15 = lane & 15;
  const int b0 = blockIdx.x * 32;
  const int hc = cw * 16 + l15;     // this thread's h-column

  for (int i = tid; i < 32 * 264; i += 1024) { h0l[i] = 0; h1l[i] = 0; }

  f32x4 c0r[2], c1r[2];             // cell state: [mt], 4 rows each
  c0r[0] = c0r[1] = c1r[0] = c1r[1] = (f32x4){0.f, 0.f, 0.f, 0.f};

  f32x4 acc[2][4];                  // [mt][gate]

  const unsigned short* bW0 = p.W0p + (size_t)(cw * 64 + l15) * 512 + q4 * 8;
  const unsigned short* bW1 = p.W1p + (size_t)(cw * 64 + l15) * 512 + q4 * 8;

  auto zacc = [&]() {
#pragma unroll
    for (int m = 0; m < 2; ++m)
#pragma unroll
      for (int g = 0; g < 4; ++g) acc[m][g] = (f32x4){0.f, 0.f, 0.f, 0.f};
  };

  // One K-half (256 = 8 ks of 32). A rows l15 / l15+16 from a0 (+lda), B dbuf'd.
  auto khalf = [&](const unsigned short* a0, int lda, const unsigned short* bW) {
    const unsigned short* a1 = a0 + (size_t)16 * lda;
    bf16x8 bf[2][4];
#pragma unroll
    for (int g = 0; g < 4; ++g) bf[0][g] = *(const bf16x8*)(bW + g * 8192);
#pragma unroll
    for (int ks = 0; ks < 8; ++ks) {
      const int cur = ks & 1, nxt = cur ^ 1;
      if (ks < 7) {
#pragma unroll
        for (int g = 0; g < 4; ++g)
          bf[nxt][g] = *(const bf16x8*)(bW + g * 8192 + (ks + 1) * 32);
      }
      bf16x8 af0 = *(const bf16x8*)(a0 + ks * 32);
      bf16x8 af1 = *(const bf16x8*)(a1 + ks * 32);
#pragma unroll
      for (int g = 0; g < 4; ++g) {
        acc[0][g] = __builtin_amdgcn_mfma_f32_16x16x32_bf16(af0, bf[cur][g], acc[0][g], 0, 0, 0);
        acc[1][g] = __builtin_amdgcn_mfma_f32_16x16x32_bf16(af1, bf[cur][g], acc[1][g], 0, 0, 0);
      }
    }
  };

  // acc[m][0..3] = i,f,g,o pre-activations for rows m*16+q4*4+r, col hc.
  auto cell = [&](f32x4 (&cr)[2], const float* bc, unsigned short* hl,
                  unsigned short* hg, float* hf, float* cf) {
    const float bI = bc[hc], bF = bc[256 + hc], bG = bc[512 + hc], bO = bc[768 + hc];
#pragma unroll
    for (int m = 0; m < 2; ++m)
#pragma unroll
      for (int r = 0; r < 4; ++r) {
        const int row = m * 16 + q4 * 4 + r;
        const float cnv = sigm(acc[m][1][r] + bF) * cr[m][r]
                        + sigm(acc[m][0][r] + bI) * tanh_fast(acc[m][2][r] + bG);
        const float hnv = sigm(acc[m][3][r] + bO) * tanh_fast(cnv);
        cr[m][r] = cnv;
        hl[row * 264 + hc] = f2bf(hnv);
        if (hg) __builtin_nontemporal_store(f2bf(hnv), hg + (size_t)(b0 + row) * HH + hc);
        if (hf) {
          hf[(size_t)(b0 + row) * HH + hc] = hnv;
          cf[(size_t)(b0 + row) * HH + hc] = cnv;
        }
      }
  };

  __syncthreads();   // h0l/h1l zero-init visible

  for (int t = 0; t < TT; ++t) {
    const bool last = (t == TT - 1);
    // ---- L0: gates = [xp_t | h0] @ W0^T ----
    zacc();
    khalf(p.xp + ((size_t)(b0 + l15) * TT + t) * HH + q4 * 8, TT * HH, bW0);  // x half
    khalf(h0l + l15 * 264 + q4 * 8, 264, bW0 + 256);                          // h0 half
    __syncthreads();   // (a) all reads of h0l done
    cell(c0r, p.bc0, h0l, nullptr,
         last ? p.hn : nullptr, last ? p.cn : nullptr);
    __syncthreads();   // (b) new h0 visible
    // ---- L1: gates = [h0 | h1] @ W1^T ----
    zacc();
    khalf(h0l + l15 * 264 + q4 * 8, 264, bW1);                                // h0 half
    khalf(h1l + l15 * 264 + q4 * 8, 264, bW1 + 256);                          // h1 half
    __syncthreads();   // (c) all reads of h1l done
    cell(c1r, p.bc1, h1l, p.hs + (size_t)(t + 1) * BB * HH,
         last ? p.hn + (size_t)BB * HH : nullptr,
         last ? p.cn + (size_t)BB * HH : nullptr);
    // no 4th barrier: h1l next read at L1(t+1), after (a,t+1)+(b,t+1)
  }
}

// Output projection: out[m=t*B+b][o] = hs[m+B][:] . Wob[o][:] + bout[o] (unchanged)
__global__ __launch_bounds__(256) void out_gemm_mfma(
    const unsigned short* __restrict__ hs,
    const unsigned short* __restrict__ Wob,
    const float* __restrict__ bout,
    float* __restrict__ out) {
  const int tid = threadIdx.x;
  const int w = tid >> 6, lane = tid & 63, quad = lane >> 4, l15 = lane & 15;
  const int m0 = blockIdx.x * 64 + w * 16;
  const unsigned short* arow = hs + (size_t)(m0 + l15 + BB) * HH + quad * 8;
  const unsigned short* brow = Wob + l15 * HH + quad * 8;
  f32x4 acc = (f32x4){0.f, 0.f, 0.f, 0.f};
#pragma unroll
  for (int k0 = 0; k0 < 8; ++k0) {
    bf16x8 a = *(const bf16x8*)(arow + k0 * 32);
    bf16x8 b = *(const bf16x8*)(brow + k0 * 32);
    acc = __builtin_amdgcn_mfma_f32_16x16x32_bf16(a, b, acc, 0, 0, 0);
  }
  const int o = l15;
  if (o < OO) {
    float bv = bout[o];
#pragma unroll
    for (int r = 0; r < 4; ++r) {
      int m = m0 + quad * 4 + r;
      int b = m & (BB - 1);
      int t = m >> 13;
      out[((size_t)b * TT + t) * OO + o] = acc[r] + bv;
    }
  }
}

extern "C" void kernel_launch(void* const* d_in, const int* in_sizes, int n_in,
                              void* d_out, int out_size, void* d_ws, size_t ws_size,
                              hipStream_t stream) {
  const float* inputs = (const float*)d_in[0];
  const float* W_inp  = (const float*)d_in[1];
  const float* b_inp  = (const float*)d_in[2];
  const float* Wih0   = (const float*)d_in[3];
  const float* Whh0   = (const float*)d_in[4];
  const float* bih0   = (const float*)d_in[5];
  const float* bhh0   = (const float*)d_in[6];
  const float* Wih1   = (const float*)d_in[7];
  const float* Whh1   = (const float*)d_in[8];
  const float* bih1   = (const float*)d_in[9];
  const float* bhh1   = (const float*)d_in[10];
  const float* W_out  = (const float*)d_in[11];
  const float* b_out  = (const float*)d_in[12];
  float* out = (float*)d_out;

  char* ws = (char*)d_ws;
  size_t off = 0;
  auto alloc = [&](size_t bytes) {
    char* p = ws + off;
    off += (bytes + 255) & ~(size_t)255;
    return p;
  };
  unsigned short* Ain = (unsigned short*)alloc((size_t)81920 * FP * 2);
  unsigned short* xp  = (unsigned short*)alloc((size_t)81920 * HH * 2);
  unsigned short* Wib = (unsigned short*)alloc((size_t)256 * FP * 2);
  unsigned short* W0p = (unsigned short*)alloc((size_t)1024 * 512 * 2);
  unsigned short* W1p = (unsigned short*)alloc((size_t)1024 * 512 * 2);
  unsigned short* Wob = (unsigned short*)alloc((size_t)16 * HH * 2);
  unsigned short* hs  = (unsigned short*)alloc((size_t)(TT + 1) * BB * HH * 2);
  float* bc0 = (float*)alloc((size_t)1024 * 4);
  float* bc1 = (float*)alloc((size_t)1024 * 4);

  conv_inputs<<<(81920 * 144 + 255) / 256, 256, 0, stream>>>(inputs, Ain);
  {
    int nthr = 256 * 576 + 2 * 1024 * 512 + 16 * 256 + 2048;
    conv_weights<<<(nthr + 255) / 256, 256, 0, stream>>>(
        W_inp, Wih0, Whh0, Wih1, Whh1, W_out, bih0, bhh0, bih1, bhh1,
        Wib, W0p, W1p, Wob, bc0, bc1);
  }

  gemm_xp<<<1280, 256, 0, stream>>>(Ain, Wib, b_inp, xp);

  float* hn_out = out + (size_t)BB * TT * OO;       // h_n [2][B][H]
  float* cn_out = hn_out + (size_t)2 * BB * HH;     // c_n [2][B][H]

  RArgs ra;
  ra.xp = xp; ra.hs = hs;
  ra.W0p = W0p; ra.W1p = W1p;
  ra.bc0 = bc0; ra.bc1 = bc1;
  ra.hn = hn_out; ra.cn = cn_out;
  lstm_rows<<<256, 1024, 0, stream>>>(ra);

  out_gemm_mfma<<<1280, 256, 0, stream>>>(hs, Wob, b_out, out);
}

// Round 7
// 1078.961 us; speedup vs baseline: 1.3097x; 1.3097x over previous
//
#include <hip/hip_runtime.h>

#define BB 8192
#define TT 10
#define FF 561
#define FP 576   // 561 padded to 18*32
#define HH 256
#define OO 12

typedef __attribute__((ext_vector_type(8))) __bf16 bf16x8;
typedef __attribute__((ext_vector_type(4))) float f32x4;

__device__ __forceinline__ unsigned short f2bf(float f) {
  unsigned int u = __float_as_uint(f);
  u += 0x7fffu + ((u >> 16) & 1u);   // round-to-nearest-even
  return (unsigned short)(u >> 16);
}
__device__ __forceinline__ float sigm(float x) { return 1.f / (1.f + __expf(-x)); }
__device__ __forceinline__ float tanh_fast(float x) { return 1.f - 2.f / (__expf(2.f * x) + 1.f); }

__device__ __forceinline__ void gl_lds16(const unsigned short* g, unsigned short* l) {
  __builtin_amdgcn_global_load_lds(
      (const __attribute__((address_space(1))) unsigned int*)g,
      (__attribute__((address_space(3))) unsigned int*)l, 16, 0, 0);
}

// 128x128 tile worth of MFMA from one LDS A/B buffer (BK=32) — used by gemm_xp
__device__ __forceinline__ void mfma_tile(const unsigned short* as, const unsigned short* bs,
                                          int w, int quad, int l15, f32x4 (&acc)[2][8]) {
  bf16x8 af[2], bfr[8];
#pragma unroll
  for (int mt = 0; mt < 2; ++mt)
    af[mt] = *(const bf16x8*)&as[(w * 32 + mt * 16 + l15) * 32 + quad * 8];
#pragma unroll
  for (int nt = 0; nt < 8; ++nt)
    bfr[nt] = *(const bf16x8*)&bs[(nt * 16 + l15) * 32 + quad * 8];
#pragma unroll
  for (int mt = 0; mt < 2; ++mt)
#pragma unroll
    for (int nt = 0; nt < 8; ++nt)
      acc[mt][nt] = __builtin_amdgcn_mfma_f32_16x16x32_bf16(af[mt], bfr[nt], acc[mt][nt], 0, 0, 0);
}

// Convert inputs [81920,561] f32 -> bf16 zero-padded [81920,576]
__global__ void conv_inputs(const float* __restrict__ in, unsigned short* __restrict__ Ain) {
  int idx = blockIdx.x * 256 + threadIdx.x;  // over 81920*144, 4 elems each
  if (idx >= 81920 * 144) return;
  int c4 = (idx % 144) * 4;
  size_t row = idx / 144;
  const float* src = in + row * 561 + c4;
  ushort4 v;
  v.x = f2bf(c4 + 0 < 561 ? src[0] : 0.f);
  v.y = f2bf(c4 + 1 < 561 ? src[1] : 0.f);
  v.z = f2bf(c4 + 2 < 561 ? src[2] : 0.f);
  v.w = f2bf(c4 + 3 < 561 ? src[3] : 0.f);
  *(ushort4*)(Ain + row * 576 + c4) = v;
}

// Build bf16 weights + combined biases.
//  Wib [256][576]: W_inp zero-padded.
//  W0p/W1p [1024][512]: permuted fused [Wih|Whh], gate-quad per 16-h-group:
//  n' -> hq=n'>>6, g=(n'>>4)&3, hl=n'&15; src row = g*256 + hq*16 + hl.
//  Wob [16][256], bc0/bc1 [1024] = bih+bhh (f32, original gate-major).
__global__ void conv_weights(const float* __restrict__ Winp,
                             const float* __restrict__ Wih0, const float* __restrict__ Whh0,
                             const float* __restrict__ Wih1, const float* __restrict__ Whh1,
                             const float* __restrict__ Wout,
                             const float* __restrict__ bih0, const float* __restrict__ bhh0,
                             const float* __restrict__ bih1, const float* __restrict__ bhh1,
                             unsigned short* __restrict__ Wib,
                             unsigned short* __restrict__ W0p,
                             unsigned short* __restrict__ W1p,
                             unsigned short* __restrict__ Wob,
                             float* __restrict__ bc0, float* __restrict__ bc1) {
  int idx = blockIdx.x * 256 + threadIdx.x;
  if (idx < 256 * 576) {
    int kk = idx % 576, n = idx / 576;
    Wib[idx] = f2bf(kk < 561 ? Winp[n * 561 + kk] : 0.f);
    return;
  }
  idx -= 256 * 576;
  if (idx < 1024 * 512) {
    int kk = idx % 512, np = idx / 512;
    int hq = np >> 6, g = (np >> 4) & 3, hl = np & 15;
    int sr = g * 256 + hq * 16 + hl;
    float v = kk < 256 ? Wih0[sr * 256 + kk] : Whh0[sr * 256 + kk - 256];
    W0p[idx] = f2bf(v);
    return;
  }
  idx -= 1024 * 512;
  if (idx < 1024 * 512) {
    int kk = idx % 512, np = idx / 512;
    int hq = np >> 6, g = (np >> 4) & 3, hl = np & 15;
    int sr = g * 256 + hq * 16 + hl;
    float v = kk < 256 ? Wih1[sr * 256 + kk] : Whh1[sr * 256 + kk - 256];
    W1p[idx] = f2bf(v);
    return;
  }
  idx -= 1024 * 512;
  if (idx < 16 * 256) {
    int kk = idx % 256, o = idx / 256;
    Wob[idx] = f2bf(o < OO ? Wout[o * 256 + kk] : 0.f);
    return;
  }
  idx -= 16 * 256;
  if (idx < 1024) { bc0[idx] = bih0[idx] + bhh0[idx]; return; }
  idx -= 1024;
  if (idx < 1024) { bc1[idx] = bih1[idx] + bhh1[idx]; }
}

// xp GEMM: xp[81920,256] = Ain @ Wib^T + b_inp. M=81920 N=256 K=576. (unchanged)
__global__ __launch_bounds__(256, 2) void gemm_xp(
    const unsigned short* __restrict__ A, const unsigned short* __restrict__ W,
    const float* __restrict__ bias, unsigned short* __restrict__ xp) {
  __shared__ __align__(16) unsigned short As[2][128 * 32];
  __shared__ __align__(16) unsigned short Bs[2][128 * 32];
  const int tid = threadIdx.x;
  const int w = tid >> 6, lane = tid & 63, quad = lane >> 4, l15 = lane & 15;
  const int flat = blockIdx.x;
  const int xcd = flat & 7, kb = flat >> 3;     // kb in [0,160)
  const int nb = kb & 1, mb = xcd * 80 + (kb >> 1);
  const int r0 = tid >> 2, cc = (tid & 3) * 8;

  auto stage = [&](int buf, int k0) {
    gl_lds16(A + (size_t)(mb * 128 + r0) * FP + k0 + cc, &As[buf][tid * 8]);
    gl_lds16(A + (size_t)(mb * 128 + 64 + r0) * FP + k0 + cc, &As[buf][2048 + tid * 8]);
    gl_lds16(W + (size_t)(nb * 128 + r0) * FP + k0 + cc, &Bs[buf][tid * 8]);
    gl_lds16(W + (size_t)(nb * 128 + 64 + r0) * FP + k0 + cc, &Bs[buf][2048 + tid * 8]);
  };

  f32x4 acc[2][8];
#pragma unroll
  for (int i = 0; i < 2; ++i)
#pragma unroll
    for (int j = 0; j < 8; ++j) acc[i][j] = (f32x4){0.f, 0.f, 0.f, 0.f};

  stage(0, 0);
  __syncthreads();
  int cur = 0;
#pragma unroll
  for (int ks = 0; ks < 17; ++ks) {
    stage(cur ^ 1, (ks + 1) * 32);
    mfma_tile(&As[cur][0], &Bs[cur][0], w, quad, l15, acc);
    __syncthreads();
    cur ^= 1;
  }
  mfma_tile(&As[cur][0], &Bs[cur][0], w, quad, l15, acc);

#pragma unroll
  for (int mt = 0; mt < 2; ++mt) {
    int rowb = mb * 128 + w * 32 + mt * 16 + quad * 4;
#pragma unroll
    for (int nt = 0; nt < 8; ++nt) {
      int col = nb * 128 + nt * 16 + l15;
      float bv = bias[col];
#pragma unroll
      for (int r = 0; r < 4; ++r)
        xp[(size_t)(rowb + r) * HH + col] = f2bf(acc[mt][nt][r] + bv);
    }
  }
}

struct RArgs {
  const unsigned short* xp;   // [81920][256], row m = b*TT + t
  unsigned short* hs;         // [(T+1)][B][H], slots 1..T written here
  const unsigned short* W0p;  // [1024][512] gate-quad permuted
  const unsigned short* W1p;
  const float* bc0;           // [1024] bih+bhh, gate-major
  const float* bc1;
  float* hn;                  // [2][B][H] f32 out
  float* cn;
};

// Exchange-free persistent LSTM with LDS-STAGED W (fix for round-6's direct-load
// L2-miss storm: FETCH 1.13GB, latency-bound). 256 blocks x 512 threads (8 waves,
// 1 block/CU, LDS ~132KB). Block owns 32 batch rows end-to-end; no inter-block
// communication. Per layer-job, W (1MB) streams L2->LDS via global_load_lds in
// [512 gates][32 k] double-buffered chunks (coalesced full lines, ~7.8us/job at
// the per-CU L2 port = the design floor). Gate-half split: half p = gates
// [512p,512p+512) = h-cols [128p,+128); wave cw owns 64 gate-cols = {i,f,g,o} x
// 16 h-cols (gate-quad W permutation) -> acc[2][4]. A-operand: x direct from
// global (all waves share one 16KB tile -> L1), h from padded ping-pong LDS
// (stride 264 -> 2-way = free). W chunk swizzle: 16B-chunk j XOR (gate&3)
// (4-way read conflict, non-binding). Cell state in registers.
__global__ __launch_bounds__(512, 1) void lstm_stage(RArgs p) {
  __shared__ __align__(16) unsigned short Wst[2][512 * 32];   // 64 KB dbuf
  __shared__ __align__(16) unsigned short h0l[2][32 * 264];   // 33.8 KB ping-pong
  __shared__ __align__(16) unsigned short h1l[2][32 * 264];   // 33.8 KB ping-pong
  const int tid = threadIdx.x;
  const int cw = tid >> 6, lane = tid & 63, q4 = lane >> 4, l15 = lane & 15;
  const int b0 = blockIdx.x * 32;

  for (int i = tid; i < 32 * 264; i += 512) { h0l[0][i] = 0; h1l[0][i] = 0; }

  f32x4 c0r[2][2], c1r[2][2];   // [half][mt], 4 rows each
#pragma unroll
  for (int a = 0; a < 2; ++a)
#pragma unroll
    for (int b = 0; b < 2; ++b) {
      c0r[a][b] = (f32x4){0.f, 0.f, 0.f, 0.f};
      c1r[a][b] = (f32x4){0.f, 0.f, 0.f, 0.f};
    }

  // Stage one [512 gates][32 k] W chunk (32KB): 512 threads x 4 gl_lds16.
  // LDS chunk n=(gate,j4) holds logical k-chunk (j4^(gate&3)) of that gate row.
  auto stageW = [&](const unsigned short* Wbase, int k0, int buf) {
#pragma unroll
    for (int j = 0; j < 4; ++j) {
      const int n = tid + j * 512;
      const int gate = n >> 2, j4 = n & 3;
      gl_lds16(Wbase + (size_t)gate * 512 + k0 + ((j4 ^ (gate & 3)) << 3),
               &Wst[buf][n * 8]);
    }
  };

  int buf = 0;
  stageW(p.W0p, 0, 0);          // prologue: first chunk of job (t0,L0,half0)
  __syncthreads();

  for (int t = 0; t < TT; ++t) {
    const int cu = t & 1, nx = cu ^ 1;
    const bool last = (t == TT - 1);
    for (int lay = 0; lay < 2; ++lay) {
      const unsigned short* Wb = lay ? p.W1p : p.W0p;
      for (int ph = 0; ph < 2; ++ph) {
        f32x4 acc[2][4];
#pragma unroll
        for (int m = 0; m < 2; ++m)
#pragma unroll
          for (int g = 0; g < 4; ++g) acc[m][g] = (f32x4){0.f, 0.f, 0.f, 0.f};

#pragma unroll
        for (int ks = 0; ks < 16; ++ks) {
          // issue next stage into the alternate buffer
          if (ks == 15) {
            int nt = t, nl = lay, np = ph + 1;
            if (np == 2) { np = 0; ++nl; if (nl == 2) { nl = 0; ++nt; } }
            if (nt < TT) {
              const unsigned short* W2 = nl ? p.W1p : p.W0p;
              stageW(W2 + (size_t)np * 512 * 512, 0, buf ^ 1);
            }
          } else {
            stageW(Wb + (size_t)ph * 512 * 512, (ks + 1) * 32, buf ^ 1);
          }
          // A fragments (rows l15 / l15+16)
          bf16x8 af0, af1;
          if (lay == 0) {
            if (ks < 8) {
              const unsigned short* a =
                  p.xp + ((size_t)(b0 + l15) * TT + t) * HH + ks * 32 + q4 * 8;
              af0 = *(const bf16x8*)a;
              af1 = *(const bf16x8*)(a + (size_t)16 * TT * HH);
            } else {
              const unsigned short* a = &h0l[cu][l15 * 264 + (ks - 8) * 32 + q4 * 8];
              af0 = *(const bf16x8*)a;
              af1 = *(const bf16x8*)(a + 16 * 264);
            }
          } else {
            if (ks < 8) {
              const unsigned short* a = &h0l[nx][l15 * 264 + ks * 32 + q4 * 8];
              af0 = *(const bf16x8*)a;
              af1 = *(const bf16x8*)(a + 16 * 264);
            } else {
              const unsigned short* a = &h1l[cu][l15 * 264 + (ks - 8) * 32 + q4 * 8];
              af0 = *(const bf16x8*)a;
              af1 = *(const bf16x8*)(a + 16 * 264);
            }
          }
          // W fragments + MFMA (4 gates x 2 row-frags)
#pragma unroll
          for (int g = 0; g < 4; ++g) {
            const int lg = cw * 64 + g * 16 + l15;
            bf16x8 bfr = *(const bf16x8*)&Wst[buf][lg * 32 + ((q4 ^ (lg & 3)) << 3)];
            acc[0][g] = __builtin_amdgcn_mfma_f32_16x16x32_bf16(af0, bfr, acc[0][g], 0, 0, 0);
            acc[1][g] = __builtin_amdgcn_mfma_f32_16x16x32_bf16(af1, bfr, acc[1][g], 0, 0, 0);
          }
          __syncthreads();   // drains vmcnt(0): next chunk resident; Wst[buf] free
          buf ^= 1;
        }

        // cell update for h-cols [ph*128 + cw*16 + l15]
        {
          const int hc = ph * 128 + cw * 16 + l15;
          const float* bc = lay ? p.bc1 : p.bc0;
          const float bI = bc[hc], bF = bc[256 + hc], bG = bc[512 + hc], bO = bc[768 + hc];
          f32x4(&cr)[2] = lay ? c1r[ph] : c0r[ph];
          unsigned short* hl = lay ? &h1l[nx][0] : &h0l[nx][0];
          float* hf = nullptr; float* cf = nullptr;
          if (last) {
            const size_t lofs = lay ? (size_t)BB * HH : 0;
            hf = p.hn + lofs; cf = p.cn + lofs;
          }
#pragma unroll
          for (int m = 0; m < 2; ++m)
#pragma unroll
            for (int r = 0; r < 4; ++r) {
              const int row = m * 16 + q4 * 4 + r;
              const float cnv = sigm(acc[m][1][r] + bF) * cr[m][r]
                              + sigm(acc[m][0][r] + bI) * tanh_fast(acc[m][2][r] + bG);
              const float hnv = sigm(acc[m][3][r] + bO) * tanh_fast(cnv);
              cr[m][r] = cnv;
              hl[row * 264 + hc] = f2bf(hnv);
              if (lay == 1)
                p.hs[(size_t)(t + 1) * BB * HH + (size_t)(b0 + row) * HH + hc] = f2bf(hnv);
              if (hf) {
                hf[(size_t)(b0 + row) * HH + hc] = hnv;
                cf[(size_t)(b0 + row) * HH + hc] = cnv;
              }
            }
        }
        __syncthreads();   // h writes visible before next segment reads them
      }
    }
  }
}

// Output projection: out[m=t*B+b][o] = hs[m+B][:] . Wob[o][:] + bout[o] (unchanged)
__global__ __launch_bounds__(256) void out_gemm_mfma(
    const unsigned short* __restrict__ hs,
    const unsigned short* __restrict__ Wob,
    const float* __restrict__ bout,
    float* __restrict__ out) {
  const int tid = threadIdx.x;
  const int w = tid >> 6, lane = tid & 63, quad = lane >> 4, l15 = lane & 15;
  const int m0 = blockIdx.x * 64 + w * 16;
  const unsigned short* arow = hs + (size_t)(m0 + l15 + BB) * HH + quad * 8;
  const unsigned short* brow = Wob + l15 * HH + quad * 8;
  f32x4 acc = (f32x4){0.f, 0.f, 0.f, 0.f};
#pragma unroll
  for (int k0 = 0; k0 < 8; ++k0) {
    bf16x8 a = *(const bf16x8*)(arow + k0 * 32);
    bf16x8 b = *(const bf16x8*)(brow + k0 * 32);
    acc = __builtin_amdgcn_mfma_f32_16x16x32_bf16(a, b, acc, 0, 0, 0);
  }
  const int o = l15;
  if (o < OO) {
    float bv = bout[o];
#pragma unroll
    for (int r = 0; r < 4; ++r) {
      int m = m0 + quad * 4 + r;
      int b = m & (BB - 1);
      int t = m >> 13;
      out[((size_t)b * TT + t) * OO + o] = acc[r] + bv;
    }
  }
}

extern "C" void kernel_launch(void* const* d_in, const int* in_sizes, int n_in,
                              void* d_out, int out_size, void* d_ws, size_t ws_size,
                              hipStream_t stream) {
  const float* inputs = (const float*)d_in[0];
  const float* W_inp  = (const float*)d_in[1];
  const float* b_inp  = (const float*)d_in[2];
  const float* Wih0   = (const float*)d_in[3];
  const float* Whh0   = (const float*)d_in[4];
  const float* bih0   = (const float*)d_in[5];
  const float* bhh0   = (const float*)d_in[6];
  const float* Wih1   = (const float*)d_in[7];
  const float* Whh1   = (const float*)d_in[8];
  const float* bih1   = (const float*)d_in[9];
  const float* bhh1   = (const float*)d_in[10];
  const float* W_out  = (const float*)d_in[11];
  const float* b_out  = (const float*)d_in[12];
  float* out = (float*)d_out;

  char* ws = (char*)d_ws;
  size_t off = 0;
  auto alloc = [&](size_t bytes) {
    char* p = ws + off;
    off += (bytes + 255) & ~(size_t)255;
    return p;
  };
  unsigned short* Ain = (unsigned short*)alloc((size_t)81920 * FP * 2);
  unsigned short* xp  = (unsigned short*)alloc((size_t)81920 * HH * 2);
  unsigned short* Wib = (unsigned short*)alloc((size_t)256 * FP * 2);
  unsigned short* W0p = (unsigned short*)alloc((size_t)1024 * 512 * 2);
  unsigned short* W1p = (unsigned short*)alloc((size_t)1024 * 512 * 2);
  unsigned short* Wob = (unsigned short*)alloc((size_t)16 * HH * 2);
  unsigned short* hs  = (unsigned short*)alloc((size_t)(TT + 1) * BB * HH * 2);
  float* bc0 = (float*)alloc((size_t)1024 * 4);
  float* bc1 = (float*)alloc((size_t)1024 * 4);

  conv_inputs<<<(81920 * 144 + 255) / 256, 256, 0, stream>>>(inputs, Ain);
  {
    int nthr = 256 * 576 + 2 * 1024 * 512 + 16 * 256 + 2048;
    conv_weights<<<(nthr + 255) / 256, 256, 0, stream>>>(
        W_inp, Wih0, Whh0, Wih1, Whh1, W_out, bih0, bhh0, bih1, bhh1,
        Wib, W0p, W1p, Wob, bc0, bc1);
  }

  gemm_xp<<<1280, 256, 0, stream>>>(Ain, Wib, b_inp, xp);

  float* hn_out = out + (size_t)BB * TT * OO;       // h_n [2][B][H]
  float* cn_out = hn_out + (size_t)2 * BB * HH;     // c_n [2][B][H]

  RArgs ra;
  ra.xp = xp; ra.hs = hs;
  ra.W0p = W0p; ra.W1p = W1p;
  ra.bc0 = bc0; ra.bc1 = bc1;
  ra.hn = hn_out; ra.cn = cn_out;
  lstm_stage<<<256, 512, 0, stream>>>(ra);

  out_gemm_mfma<<<1280, 256, 0, stream>>>(hs, Wob, b_out, out);
}